// Round 1
// baseline (1137.564 us; speedup 1.0000x reference)
//
#include <hip/hip_runtime.h>

// BKT 2-state HMM forward-backward.
// B=8192 chains, T=1024 steps. One thread per chain.
// Outputs (3,B,T,2) fp32: [pred logprobs, state posteriors (unnormalized log-joint), smoothed].

#define BB 8192
#define TT 1024

__device__ __forceinline__ float softplusf(float x) {
    // log(1 + exp(x)) = max(x,0) + log(1 + exp(-|x|))
    return fmaxf(x, 0.0f) + __logf(1.0f + __expf(-fabsf(x)));
}

__device__ __forceinline__ float lse2(float a, float b) {
    float m = fmaxf(a, b);
    return m + __logf(1.0f + __expf(-fabsf(a - b)));
}

__global__ void bkt_kernel(const int* __restrict__ corr,
                           const float* __restrict__ dyn,
                           const float* __restrict__ obs,
                           float* __restrict__ out) {
    int b = blockIdx.x * blockDim.x + threadIdx.x;
    if (b >= BB) return;

    const long long S = (long long)BB * TT;  // per-section element pairs

    float d0 = dyn[b * 3 + 0];
    float d1 = dyn[b * 3 + 1];
    float d2 = dyn[b * 3 + 2];
    float sd0 = softplusf(d0), sd1 = softplusf(d1), sd2 = softplusf(d2);
    // log_t[i][j]: column-softmax of [[0, d1],[d0, 0]]
    float lt00 = -sd0;       // i=0,j=0
    float lt10 = d0 - sd0;   // i=1,j=0
    float lt01 = d1 - sd1;   // i=0,j=1
    float lt11 = -sd1;       // i=1,j=1
    float a0 = -sd2, a1 = d2 - sd2;  // log_alpha0

    const float2* obs2 = (const float2*)obs;   // (B,T,2)
    float2* out0 = (float2*)out;               // pred logprobs
    float2* out1 = ((float2*)out) + S;         // state posteriors
    float2* out2 = ((float2*)out) + 2 * S;     // smoothed

    long long base = (long long)b * TT;

    // ---- forward ----
    for (int t = 0; t < TT; ++t) {
        long long idx = base + t;
        float2 o = obs2[idx];
        int y = corr[idx];
        float sp0 = softplusf(o.x), sp1 = softplusf(o.y);
        // log_obs: row i=0: [-sp0, o0-sp0]; row i=1: [o1-sp1, -sp1]
        float lo00 = -sp0,      lo01 = o.x - sp0;
        float lo10 = o.y - sp1, lo11 = -sp1;
        // predictive p(y_t | y_<t)
        float p0 = lse2(lo00 + a0, lo10 + a1);
        float p1 = lse2(lo01 + a0, lo11 + a1);
        float n  = lse2(p0, p1);
        out0[idx] = make_float2(p0 - n, p1 - n);
        // emission of observed symbol
        float py0 = y ? lo01 : lo00;
        float py1 = y ? lo11 : lo10;
        float s0 = py0 + a0, s1 = py1 + a1;   // log P(h_t, y_1:t)
        out1[idx] = make_float2(s0, s1);
        // new_alpha[i] = lse_j(py[j] + a[j] + lt[i][j])
        float na0 = lse2(s0 + lt00, s1 + lt01);
        float na1 = lse2(s0 + lt10, s1 + lt11);
        a0 = na0; a1 = na1;
    }

    // ---- backward + smoothed (fused) ----
    float b0 = 0.0f, b1 = 0.0f;
    for (int t = TT - 1; t >= 0; --t) {
        long long idx = base + t;
        // betas[t] is beta BEFORE consuming step t (time-aligned)
        float2 post = out1[idx];
        float s0 = post.x + b0, s1 = post.y + b1;
        float n = lse2(s0, s1);
        out2[idx] = make_float2(s0 - n, s1 - n);
        // update beta with step-t quantities
        float2 o = obs2[idx];
        int y = corr[idx];
        float sp0 = softplusf(o.x), sp1 = softplusf(o.y);
        float py0 = y ? (o.x - sp0) : (-sp0);
        float py1 = y ? (-sp1) : (o.y - sp1);
        // new_beta[j] = lse_i(py[i] + beta[i] + lt[i][j])
        float nb0 = lse2(py0 + b0 + lt00, py1 + b1 + lt10);
        float nb1 = lse2(py0 + b0 + lt01, py1 + b1 + lt11);
        b0 = nb0; b1 = nb1;
    }
}

extern "C" void kernel_launch(void* const* d_in, const int* in_sizes, int n_in,
                              void* d_out, int out_size, void* d_ws, size_t ws_size,
                              hipStream_t stream) {
    const int*   corr = (const int*)d_in[0];
    const float* dyn  = (const float*)d_in[1];
    const float* obs  = (const float*)d_in[2];
    float* out = (float*)d_out;

    // block=64: 128 blocks spread over CUs; occupancy-limited by design this round.
    dim3 block(64);
    dim3 grid((BB + 63) / 64);
    bkt_kernel<<<grid, block, 0, stream>>>(corr, dyn, obs, out);
}

// Round 2
// 474.121 us; speedup vs baseline: 2.3993x; 2.3993x over previous
//
#include <hip/hip_runtime.h>

// BKT 2-state HMM forward-backward, chunked-scan version.
// B=8192 chains, T=1024. Each chain split into NC=32 chunks of KC=32 steps.
// Phase 1: per-chunk composite 2x2 log-semiring matrices (fwd + bwd, one pass).
// Phase 2: per-chain serial scan over chunk composites in LDS (tiny).
// Phase 3: replay each chunk with correct boundary alpha/beta, register-tiled
//          full-cache-line loads/stores (4x float4 per 8-step tile per stream).

#define BB 8192
#define TT 1024
#define KC 32            // steps per chunk
#define NC (TT / KC)     // 32 chunks per chain
#define GG 8             // chains per block
#define NTHREADS (GG * NC)  // 256

__device__ __forceinline__ float softplusf(float x) {
    return fmaxf(x, 0.0f) + __logf(1.0f + __expf(-fabsf(x)));
}
__device__ __forceinline__ float lse2(float a, float b) {
    float m = fmaxf(a, b);
    return m + __logf(1.0f + __expf(-fabsf(a - b)));
}

__global__ __launch_bounds__(NTHREADS) void bkt_kernel(
        const int* __restrict__ corr,
        const float* __restrict__ dyn,
        const float* __restrict__ obs,
        float* __restrict__ out) {
    __shared__ float sF[GG][NC][4];   // fwd chunk composites
    __shared__ float sBw[GG][NC][4];  // bwd chunk composites
    __shared__ float sA[GG][NC][2];   // alpha at chunk entry
    __shared__ float sBe[GG][NC][2];  // beta aligned at chunk end

    const int tid = threadIdx.x;
    const int g = tid >> 5;          // chain within block (tid / NC)
    const int c = tid & (NC - 1);    // chunk index
    const int b = blockIdx.x * GG + g;

    const float d0 = dyn[b * 3 + 0];
    const float d1 = dyn[b * 3 + 1];
    const float sd0 = softplusf(d0), sd1 = softplusf(d1);
    // log_t[i][j]: column-softmax of [[0,d1],[d0,0]]
    const float lt00 = -sd0, lt10 = d0 - sd0, lt01 = d1 - sd1, lt11 = -sd1;

    const float2* obs2 = (const float2*)obs;
    const long long S = (long long)BB * TT;
    const long long cb = (long long)b * TT + c * KC;  // chunk base (float2 index)

    float2* out0 = (float2*)out;       // pred logprobs
    float2* out1 = out0 + S;           // state posteriors (log-joint)
    float2* out2 = out1 + S;           // smoothed

    // ---------------- Phase 1: chunk composites (fwd F, bwd Bw) --------------
    float F00, F01, F10, F11, B00, B01, B10, B11;
    {
        bool first = true;
        for (int tt = 0; tt < KC; tt += 8) {
            const float4* op = (const float4*)(obs2 + cb + tt);
            float4 o4[4] = {op[0], op[1], op[2], op[3]};
            const int4* yp = (const int4*)(corr + cb + tt);
            int4 ya = yp[0], yb = yp[1];
            int ys[8] = {ya.x, ya.y, ya.z, ya.w, yb.x, yb.y, yb.z, yb.w};
            float ox[8] = {o4[0].x, o4[0].z, o4[1].x, o4[1].z, o4[2].x, o4[2].z, o4[3].x, o4[3].z};
            float oy[8] = {o4[0].y, o4[0].w, o4[1].y, o4[1].w, o4[2].y, o4[2].w, o4[3].y, o4[3].w};
            #pragma unroll
            for (int s = 0; s < 8; ++s) {
                float sp0 = softplusf(ox[s]), sp1 = softplusf(oy[s]);
                float py0 = ys[s] ? (ox[s] - sp0) : (-sp0);
                float py1 = ys[s] ? (-sp1) : (oy[s] - sp1);
                // fwd step map N[i][j] = py[j] + lt[i][j]
                float N00 = py0 + lt00, N01 = py1 + lt01;
                float N10 = py0 + lt10, N11 = py1 + lt11;
                // bwd step map Q[j][i] = py[i] + lt[i][j]
                float Q00 = py0 + lt00, Q01 = py1 + lt10;
                float Q10 = py0 + lt01, Q11 = py1 + lt11;
                if (first) {
                    F00 = N00; F01 = N01; F10 = N10; F11 = N11;
                    B00 = Q00; B01 = Q01; B10 = Q10; B11 = Q11;
                    first = false;
                } else {
                    // F := N * F   (left-compose, ascending t)
                    float nF00 = lse2(N00 + F00, N01 + F10);
                    float nF01 = lse2(N00 + F01, N01 + F11);
                    float nF10 = lse2(N10 + F00, N11 + F10);
                    float nF11 = lse2(N10 + F01, N11 + F11);
                    F00 = nF00; F01 = nF01; F10 = nF10; F11 = nF11;
                    // Bw := Bw * Q  (right-compose -> earliest t applied last)
                    float nB00 = lse2(B00 + Q00, B01 + Q10);
                    float nB01 = lse2(B00 + Q01, B01 + Q11);
                    float nB10 = lse2(B10 + Q00, B11 + Q10);
                    float nB11 = lse2(B10 + Q01, B11 + Q11);
                    B00 = nB00; B01 = nB01; B10 = nB10; B11 = nB11;
                }
            }
        }
        sF[g][c][0] = F00; sF[g][c][1] = F01; sF[g][c][2] = F10; sF[g][c][3] = F11;
        sBw[g][c][0] = B00; sBw[g][c][1] = B01; sBw[g][c][2] = B10; sBw[g][c][3] = B11;
    }
    __syncthreads();

    // ---------------- Phase 2: per-chain scans over chunks --------------------
    if (c == 0) {
        const float d2 = dyn[b * 3 + 2];
        const float sd2 = softplusf(d2);
        float a0 = -sd2, a1 = d2 - sd2;
        sA[g][0][0] = a0; sA[g][0][1] = a1;
        for (int cc = 0; cc < NC - 1; ++cc) {
            float f00 = sF[g][cc][0], f01 = sF[g][cc][1];
            float f10 = sF[g][cc][2], f11 = sF[g][cc][3];
            float na0 = lse2(f00 + a0, f01 + a1);
            float na1 = lse2(f10 + a0, f11 + a1);
            a0 = na0; a1 = na1;
            sA[g][cc + 1][0] = a0; sA[g][cc + 1][1] = a1;
        }
    } else if (c == 1) {
        float b0 = 0.0f, b1 = 0.0f;
        sBe[g][NC - 1][0] = 0.0f; sBe[g][NC - 1][1] = 0.0f;
        for (int cc = NC - 1; cc >= 1; --cc) {
            float q00 = sBw[g][cc][0], q01 = sBw[g][cc][1];
            float q10 = sBw[g][cc][2], q11 = sBw[g][cc][3];
            float nb0 = lse2(q00 + b0, q01 + b1);
            float nb1 = lse2(q10 + b0, q11 + b1);
            b0 = nb0; b1 = nb1;
            sBe[g][cc - 1][0] = b0; sBe[g][cc - 1][1] = b1;
        }
    }
    __syncthreads();

    // ---------------- Phase 3a: forward replay ------------------------------
    {
        float a0 = sA[g][c][0], a1 = sA[g][c][1];
        for (int tt = 0; tt < KC; tt += 8) {
            const float4* op = (const float4*)(obs2 + cb + tt);
            float4 o4[4] = {op[0], op[1], op[2], op[3]};
            const int4* yp = (const int4*)(corr + cb + tt);
            int4 ya = yp[0], yb = yp[1];
            int ys[8] = {ya.x, ya.y, ya.z, ya.w, yb.x, yb.y, yb.z, yb.w};
            float ox[8] = {o4[0].x, o4[0].z, o4[1].x, o4[1].z, o4[2].x, o4[2].z, o4[3].x, o4[3].z};
            float oy[8] = {o4[0].y, o4[0].w, o4[1].y, o4[1].w, o4[2].y, o4[2].w, o4[3].y, o4[3].w};
            float w0[16], w1[16];
            #pragma unroll
            for (int s = 0; s < 8; ++s) {
                float sp0 = softplusf(ox[s]), sp1 = softplusf(oy[s]);
                float lo00 = -sp0,        lo01 = ox[s] - sp0;
                float lo10 = oy[s] - sp1, lo11 = -sp1;
                float p0 = lse2(lo00 + a0, lo10 + a1);
                float p1 = lse2(lo01 + a0, lo11 + a1);
                float n = lse2(p0, p1);
                w0[2 * s] = p0 - n; w0[2 * s + 1] = p1 - n;
                float py0 = ys[s] ? lo01 : lo00;
                float py1 = ys[s] ? lo11 : lo10;
                float s0 = py0 + a0, s1 = py1 + a1;
                w0[2 * s] = p0 - n;      // (kept explicit)
                w1[2 * s] = s0; w1[2 * s + 1] = s1;
                float na0 = lse2(s0 + lt00, s1 + lt01);
                float na1 = lse2(s0 + lt10, s1 + lt11);
                a0 = na0; a1 = na1;
            }
            float4* d0p = (float4*)(out0 + cb + tt);
            float4* d1p = (float4*)(out1 + cb + tt);
            #pragma unroll
            for (int k = 0; k < 4; ++k) {
                d0p[k] = make_float4(w0[4 * k], w0[4 * k + 1], w0[4 * k + 2], w0[4 * k + 3]);
                d1p[k] = make_float4(w1[4 * k], w1[4 * k + 1], w1[4 * k + 2], w1[4 * k + 3]);
            }
        }
    }

    // ---------------- Phase 3b: backward replay + smoothed -------------------
    {
        float be0 = sBe[g][c][0], be1 = sBe[g][c][1];  // beta aligned at chunk end
        for (int tt = KC - 8; tt >= 0; tt -= 8) {
            const float4* op = (const float4*)(obs2 + cb + tt);
            float4 o4[4] = {op[0], op[1], op[2], op[3]};
            const int4* yp = (const int4*)(corr + cb + tt);
            int4 ya = yp[0], yb = yp[1];
            int ys[8] = {ya.x, ya.y, ya.z, ya.w, yb.x, yb.y, yb.z, yb.w};
            float ox[8] = {o4[0].x, o4[0].z, o4[1].x, o4[1].z, o4[2].x, o4[2].z, o4[3].x, o4[3].z};
            float oy[8] = {o4[0].y, o4[0].w, o4[1].y, o4[1].w, o4[2].y, o4[2].w, o4[3].y, o4[3].w};
            const float4* pp = (const float4*)(out1 + cb + tt);
            float4 p4[4] = {pp[0], pp[1], pp[2], pp[3]};
            float ps[16] = {p4[0].x, p4[0].y, p4[0].z, p4[0].w,
                            p4[1].x, p4[1].y, p4[1].z, p4[1].w,
                            p4[2].x, p4[2].y, p4[2].z, p4[2].w,
                            p4[3].x, p4[3].y, p4[3].z, p4[3].w};
            float w2[16];
            #pragma unroll
            for (int s = 7; s >= 0; --s) {
                // smoothed at t uses current beta (aligned at t)
                float s0 = ps[2 * s] + be0, s1 = ps[2 * s + 1] + be1;
                float n = lse2(s0, s1);
                w2[2 * s] = s0 - n; w2[2 * s + 1] = s1 - n;
                // advance beta to t-1
                float sp0 = softplusf(ox[s]), sp1 = softplusf(oy[s]);
                float py0 = ys[s] ? (ox[s] - sp0) : (-sp0);
                float py1 = ys[s] ? (-sp1) : (oy[s] - sp1);
                float nb0 = lse2(py0 + be0 + lt00, py1 + be1 + lt10);
                float nb1 = lse2(py0 + be0 + lt01, py1 + be1 + lt11);
                be0 = nb0; be1 = nb1;
            }
            float4* d2p = (float4*)(out2 + cb + tt);
            #pragma unroll
            for (int k = 0; k < 4; ++k) {
                d2p[k] = make_float4(w2[4 * k], w2[4 * k + 1], w2[4 * k + 2], w2[4 * k + 3]);
            }
        }
    }
}

extern "C" void kernel_launch(void* const* d_in, const int* in_sizes, int n_in,
                              void* d_out, int out_size, void* d_ws, size_t ws_size,
                              hipStream_t stream) {
    const int*   corr = (const int*)d_in[0];
    const float* dyn  = (const float*)d_in[1];
    const float* obs  = (const float*)d_in[2];
    float* out = (float*)d_out;

    dim3 block(NTHREADS);                // 256 = 8 chains x 32 chunks
    dim3 grid(BB / GG);                  // 1024 blocks -> 4096 waves, ~4/SIMD
    bkt_kernel<<<grid, block, 0, stream>>>(corr, dyn, obs, out);
}